// Round 3
// baseline (1172.031 us; speedup 1.0000x reference)
//
#include <hip/hip_runtime.h>

// ---------------------------------------------------------------- constants
#define SCALEF 0.17677669529663687f  // 32^-0.5

typedef __attribute__((ext_vector_type(8))) short short8;   // 8 bf16
typedef __attribute__((ext_vector_type(4))) float f32x4;

__device__ __forceinline__ unsigned short f2bf(float f) {
  unsigned u = __builtin_bit_cast(unsigned, f);
  u = (u + 0x7FFFu + ((u >> 16) & 1u)) >> 16;
  return (unsigned short)u;
}

__device__ __forceinline__ short8 ld8(const unsigned short* p) {
  return *(const short8*)p;
}

// ---------------------------------------------------------------- K0a: weights fp32 -> bf16
// layout (elements): qkv_w [0,49152) proj_w [49152,65536) fc1_w [65536,131072) fc2_w [131072,196608)
__global__ __launch_bounds__(256) void k_cvt(const float* qkvw, const float* projw,
                                             const float* fc1w, const float* fc2w,
                                             unsigned short* wbuf) {
  int i = blockIdx.x * 256 + threadIdx.x;
  float v;
  if (i < 49152) v = qkvw[i];
  else if (i < 65536) v = projw[i - 49152];
  else if (i < 131072) v = fc1w[i - 65536];
  else v = fc2w[i - 131072];
  wbuf[i] = f2bf(v);
}

// ---------------------------------------------------------------- K0b: bias+mask table
// add[w][h][i][j], w=window-in-image (0..63), h=head, i,j in 0..48
__device__ __forceinline__ int regio(int r) { return r < 49 ? 0 : (r < 53 ? 1 : 2); }

__global__ __launch_bounds__(256) void k_addtab(const float* rpb, float* at) {
  int idx = blockIdx.x * 256 + threadIdx.x;      // exactly 64*4*49*49 = 614656 threads
  int j = idx % 49;
  int tmp = idx / 49;
  int i = tmp % 49; tmp /= 49;
  int h = tmp & 3;
  int w = tmp >> 2;
  int ih = i / 7, iw = i % 7, jh = j / 7, jw = j % 7;
  int rpi = (ih - jh + 6) * 13 + (iw - jw + 6);
  float bias = rpb[rpi * 4 + h];
  int wr = w >> 3, wc = w & 7;
  int idi = regio(wr * 7 + ih) * 3 + regio(wc * 7 + iw);
  int idj = regio(wr * 7 + jh) * 3 + regio(wc * 7 + jw);
  at[idx] = bias + ((idi != idj) ? -100.0f : 0.0f);
}

// ---------------------------------------------------------------- K1: fused LN1 + QKV + attention + proj + residual
// 1 block / window (4096 blocks), 4 waves.
// LDS: R1 (32 KB) holds Xw (49x128 bf16, swizzled) in phase 0-1, per-wave P
//      tiles (4 x 64x64 bf16) in phase 2.
//      QKVl (48 KB) holds the 64x384 QKV tile (swizzled); after PV its
//      Q-section (bytes [0,256) per row) is reused for the 64x128 attention
//      output tile that feeds proj.
__global__ __launch_bounds__(256) void k_attn(const float* __restrict__ x,
                                              const float* __restrict__ g1,
                                              const float* __restrict__ b1,
                                              const unsigned short* __restrict__ wq,
                                              const float* __restrict__ qb,
                                              const unsigned short* __restrict__ wp,
                                              const float* __restrict__ pb,
                                              const float* __restrict__ addtab,
                                              float* __restrict__ y) {
  __shared__ unsigned short R1s[16384];      // 32 KB
  __shared__ unsigned short QKVl[64 * 384];  // 48 KB

  int g = blockIdx.x;
  int wv = threadIdx.x >> 6, l = threadIdx.x & 63;
  int lo = l & 15, hi = l >> 4;
  int bimg = g >> 6, w_in = g & 63;
  int wr = w_in >> 3, wc = w_in & 7;

  // ---- Phase 0: LN1 + roll(-3,-3) gather -> Xw (bf16, swizzled)
  for (int r = wv; r < 49; r += 4) {
    int ih = r / 7, iw = r - ih * 7;
    int oh = wr * 7 + ih + 3; if (oh >= 56) oh -= 56;
    int ow = wc * 7 + iw + 3; if (ow >= 56) ow -= 56;
    const float* src = x + ((size_t)bimg * 3136 + oh * 56 + ow) * 128;
    float2 v = *(const float2*)(src + l * 2);
    float s = v.x + v.y;
    #pragma unroll
    for (int off = 32; off; off >>= 1) s += __shfl_xor(s, off);
    float mu = s * (1.0f / 128.0f);
    float dx = v.x - mu, dy = v.y - mu;
    float q = dx * dx + dy * dy;
    #pragma unroll
    for (int off = 32; off; off >>= 1) q += __shfl_xor(q, off);
    float rs = rsqrtf(q * (1.0f / 128.0f) + 1e-5f);
    float o0 = dx * rs * g1[2 * l] + b1[2 * l];
    float o1 = dy * rs * g1[2 * l + 1] + b1[2 * l + 1];
    unsigned pk = (unsigned)f2bf(o0) | ((unsigned)f2bf(o1) << 16);
    *(unsigned*)((char*)R1s + r * 256 + ((l * 4) ^ ((r & 7) << 4))) = pk;
  }
  __syncthreads();

  // ---- Phase 1: QKV = Xw @ Wqkv^T + b; wave wv -> cols [wv*96, wv*96+96)
  int nbase = wv * 96;
  #pragma unroll 1
  for (int mt = 0; mt < 4; mt++) {
    int ar = mt * 16 + lo; if (ar > 48) ar = 48;
    short8 a[4];
    #pragma unroll
    for (int ks = 0; ks < 4; ks++)
      a[ks] = *(const short8*)((char*)R1s + ar * 256 + ((hi * 16 + ks * 64) ^ ((ar & 7) << 4)));
    f32x4 acc[6] = {};
    #pragma unroll
    for (int ks = 0; ks < 4; ks++)
      #pragma unroll
      for (int tj = 0; tj < 6; tj++) {
        int n = nbase + tj * 16 + lo;
        short8 b = ld8(wq + (size_t)n * 128 + hi * 8 + ks * 32);
        acc[tj] = __builtin_amdgcn_mfma_f32_16x16x32_bf16(a[ks], b, acc[tj], 0, 0, 0);
      }
    #pragma unroll
    for (int tj = 0; tj < 6; tj++) {
      int n = nbase + tj * 16 + lo;
      float bias = qb[n];
      #pragma unroll
      for (int r = 0; r < 4; r++) {
        int row = mt * 16 + hi * 4 + r;
        int bo = row * 768 + ((n * 2) ^ ((row & 7) << 4));
        *(unsigned short*)((char*)QKVl + bo) = f2bf(acc[tj][r] + bias);
      }
    }
  }
  __syncthreads();

  // ---- Phase 2: attention for head h = wv
  int h = wv;
  short8 qf[4], kf[4];
  #pragma unroll
  for (int t = 0; t < 4; t++) {
    int tq = t * 16 + lo; if (tq > 48) tq = 48;
    int qo = tq * 768 + ((h * 64 + hi * 16) ^ ((tq & 7) << 4));
    int ko = tq * 768 + ((256 + h * 64 + hi * 16) ^ ((tq & 7) << 4));
    qf[t] = *(const short8*)((char*)QKVl + qo);
    kf[t] = *(const short8*)((char*)QKVl + ko);
  }
  // barrier: Q-section bytes get overwritten by attention-output writes below,
  // and the XOR swizzle interleaves adjacent heads' byte ranges.
  __syncthreads();

  f32x4 s[4][4] = {};
  #pragma unroll
  for (int ti = 0; ti < 4; ti++)
    #pragma unroll
    for (int tj = 0; tj < 4; tj++)
      s[ti][tj] = __builtin_amdgcn_mfma_f32_16x16x32_bf16(qf[ti], kf[tj], s[ti][tj], 0, 0, 0);

  unsigned short* Ph = R1s + h * 4096;   // per-wave 64x64 bf16 P tile (aliases Xw)
  const float* at = addtab + ((size_t)w_in * 4 + h) * 2401;
  #pragma unroll
  for (int ti = 0; ti < 4; ti++) {
    #pragma unroll
    for (int r = 0; r < 4; r++) {
      int i = ti * 16 + hi * 4 + r;
      bool iv = i < 49;
      float vv[4];
      #pragma unroll
      for (int tj = 0; tj < 4; tj++) {
        int j = tj * 16 + lo;
        float sv = s[ti][tj][r] * SCALEF;
        if (iv && j < 49) sv += at[i * 49 + j];
        vv[tj] = (j < 49) ? sv : -1e30f;
      }
      float mx = fmaxf(fmaxf(vv[0], vv[1]), fmaxf(vv[2], vv[3]));
      mx = fmaxf(mx, __shfl_xor(mx, 1)); mx = fmaxf(mx, __shfl_xor(mx, 2));
      mx = fmaxf(mx, __shfl_xor(mx, 4)); mx = fmaxf(mx, __shfl_xor(mx, 8));
      float sum = 0.0f, ev[4];
      #pragma unroll
      for (int tj = 0; tj < 4; tj++) { ev[tj] = __expf(vv[tj] - mx); sum += ev[tj]; }
      sum += __shfl_xor(sum, 1); sum += __shfl_xor(sum, 2);
      sum += __shfl_xor(sum, 4); sum += __shfl_xor(sum, 8);
      float rinv = 1.0f / sum;
      #pragma unroll
      for (int tj = 0; tj < 4; tj++) {
        int j = tj * 16 + lo;
        Ph[(i << 6) + (j ^ ((i & 7) << 3))] = f2bf(ev[tj] * rinv);
      }
    }
  }
  // PV: out[i][d] = sum_j P[i][j] V[j][d];  V[j][d] = QKVl[row j][256 + h*32 + d]
  f32x4 o[4][2] = {};
  #pragma unroll
  for (int ks = 0; ks < 2; ks++) {
    short8 pa[4];
    #pragma unroll
    for (int ti = 0; ti < 4; ti++) {
      int prow = ti * 16 + lo;
      int pj = ks * 32 + hi * 8;
      pa[ti] = *(const short8*)&Ph[(prow << 6) + (pj ^ ((prow & 7) << 3))];
    }
    #pragma unroll
    for (int td = 0; td < 2; td++) {
      short8 vf;
      #pragma unroll
      for (int e = 0; e < 8; e++) {
        int j = ks * 32 + hi * 8 + e; if (j > 48) j = 48;
        int vo = j * 768 + (((512 + h * 64) + (td * 16 + lo) * 2) ^ ((j & 7) << 4));
        vf[e] = *(const short*)((char*)QKVl + vo);
      }
      #pragma unroll
      for (int ti = 0; ti < 4; ti++)
        o[ti][td] = __builtin_amdgcn_mfma_f32_16x16x32_bf16(pa[ti], vf, o[ti][td], 0, 0, 0);
    }
  }
  // write attention output tile into the Q-section of QKVl (bytes [0,256) per
  // row, swizzled). Wave h owns cols h*32..h*32+31 for all rows; disjoint from
  // the V-section other waves may still be reading.
  #pragma unroll
  for (int ti = 0; ti < 4; ti++)
    #pragma unroll
    for (int td = 0; td < 2; td++)
      #pragma unroll
      for (int r = 0; r < 4; r++) {
        int i = ti * 16 + hi * 4 + r;
        int c = h * 32 + td * 16 + lo;
        int bo = i * 768 + ((c * 2) ^ ((i & 7) << 4));
        *(unsigned short*)((char*)QKVl + bo) = f2bf(o[ti][td][r]);
      }
  __syncthreads();

  // ---- Phase 3: proj + window-reverse + roll(+3) + residual
  int ar = wv * 16 + lo; if (ar > 48) ar = 48;
  short8 a[4];
  #pragma unroll
  for (int ks = 0; ks < 4; ks++)
    a[ks] = *(const short8*)((char*)QKVl + ar * 768 + ((hi * 16 + ks * 64) ^ ((ar & 7) << 4)));
  f32x4 acc[8] = {};
  #pragma unroll
  for (int ks = 0; ks < 4; ks++)
    #pragma unroll
    for (int tj = 0; tj < 8; tj++) {
      short8 b = ld8(wp + (size_t)(tj * 16 + lo) * 128 + hi * 8 + ks * 32);
      acc[tj] = __builtin_amdgcn_mfma_f32_16x16x32_bf16(a[ks], b, acc[tj], 0, 0, 0);
    }
  #pragma unroll
  for (int r = 0; r < 4; r++) {
    int mloc = wv * 16 + hi * 4 + r;
    if (mloc < 49) {
      int ih = mloc / 7, iw = mloc - ih * 7;
      int oh = wr * 7 + ih + 3; if (oh >= 56) oh -= 56;
      int ow = wc * 7 + iw + 3; if (ow >= 56) ow -= 56;
      size_t yrow = (size_t)bimg * 3136 + oh * 56 + ow;
      const float* xr = x + yrow * 128;
      float* yr = y + yrow * 128;
      #pragma unroll
      for (int tj = 0; tj < 8; tj++) {
        int c = tj * 16 + lo;
        yr[c] = acc[tj][r] + pb[c] + xr[c];
      }
    }
  }
}

// ---------------------------------------------------------------- K2: fused LN2 + fc1 + GELU + fc2 + residual (in-place on y)
__global__ __launch_bounds__(256) void k_mlp(float* __restrict__ y,
                                             const float* __restrict__ g2, const float* __restrict__ b2,
                                             const unsigned short* __restrict__ w1, const float* __restrict__ bias1,
                                             const unsigned short* __restrict__ w2, const float* __restrict__ bias2) {
  __shared__ unsigned short Xl[64 * 128];   // 16 KB, XOR-swizzled bf16
  __shared__ unsigned short Hl[64 * 512];   // 64 KB, XOR-swizzled bf16
  int m0 = blockIdx.x * 64;
  int wv = threadIdx.x >> 6, l = threadIdx.x & 63;
  int lo = l & 15, hi = l >> 4;

  // --- LN2
  for (int i = 0; i < 16; i++) {
    int rloc = wv * 16 + i;
    int m = m0 + rloc;
    float2 v = *(const float2*)(y + (size_t)m * 128 + l * 2);
    float s = v.x + v.y;
    #pragma unroll
    for (int off = 32; off; off >>= 1) s += __shfl_xor(s, off);
    float mu = s * (1.0f / 128.0f);
    float dx = v.x - mu, dy = v.y - mu;
    float q = dx * dx + dy * dy;
    #pragma unroll
    for (int off = 32; off; off >>= 1) q += __shfl_xor(q, off);
    float rs = rsqrtf(q * (1.0f / 128.0f) + 1e-5f);
    float o0 = dx * rs * g2[2 * l] + b2[2 * l];
    float o1 = dy * rs * g2[2 * l + 1] + b2[2 * l + 1];
    unsigned pk = (unsigned)f2bf(o0) | ((unsigned)f2bf(o1) << 16);
    int bo = (rloc * 256 + l * 4) ^ ((rloc & 7) << 4);
    *(unsigned*)((char*)Xl + bo) = pk;
  }
  __syncthreads();

  // --- fc1 + GELU
  int arow = wv * 16 + lo;
  short8 a1[4];
  #pragma unroll
  for (int ks = 0; ks < 4; ks++) {
    int bo = (arow * 256 + hi * 16 + ks * 64) ^ ((arow & 7) << 4);
    a1[ks] = *(const short8*)((char*)Xl + bo);
  }
  #pragma unroll 1
  for (int ch = 0; ch < 8; ch++) {
    f32x4 acc[4] = {};
    #pragma unroll
    for (int ks = 0; ks < 4; ks++)
      #pragma unroll
      for (int tj = 0; tj < 4; tj++) {
        int n = ch * 64 + tj * 16 + lo;
        short8 b = ld8(w1 + (size_t)n * 128 + hi * 8 + ks * 32);
        acc[tj] = __builtin_amdgcn_mfma_f32_16x16x32_bf16(a1[ks], b, acc[tj], 0, 0, 0);
      }
    #pragma unroll
    for (int tj = 0; tj < 4; tj++) {
      int n = ch * 64 + tj * 16 + lo;
      float bias = bias1[n];
      #pragma unroll
      for (int r = 0; r < 4; r++) {
        int rloc = wv * 16 + hi * 4 + r;
        float xv = acc[tj][r] + bias;
        float ge = 0.5f * xv * (1.0f + erff(xv * 0.7071067811865476f));
        int bo = (rloc * 1024 + n * 2) ^ ((rloc & 7) << 4);
        *(unsigned short*)((char*)Hl + bo) = f2bf(ge);
      }
    }
  }
  __syncthreads();

  // --- fc2
  f32x4 acc2[8] = {};
  #pragma unroll 1
  for (int ks = 0; ks < 16; ks++) {
    int bo = (arow * 1024 + hi * 16 + ks * 64) ^ ((arow & 7) << 4);
    short8 a2 = *(const short8*)((char*)Hl + bo);
    #pragma unroll
    for (int tj = 0; tj < 8; tj++) {
      short8 b = ld8(w2 + (size_t)(tj * 16 + lo) * 512 + hi * 8 + ks * 32);
      acc2[tj] = __builtin_amdgcn_mfma_f32_16x16x32_bf16(a2, b, acc2[tj], 0, 0, 0);
    }
  }
  #pragma unroll
  for (int tj = 0; tj < 8; tj++) {
    int c = tj * 16 + lo;
    float bias = bias2[c];
    #pragma unroll
    for (int r = 0; r < 4; r++) {
      int m = m0 + wv * 16 + hi * 4 + r;
      float v = acc2[tj][r] + bias + y[(size_t)m * 128 + c];
      y[(size_t)m * 128 + c] = v;
    }
  }
}

// ---------------------------------------------------------------- launch
extern "C" void kernel_launch(void* const* d_in, const int* in_sizes, int n_in,
                              void* d_out, int out_size, void* d_ws, size_t ws_size,
                              hipStream_t stream) {
  const float* x     = (const float*)d_in[0];
  const float* ln1g  = (const float*)d_in[1];
  const float* ln1b  = (const float*)d_in[2];
  const float* qkvw  = (const float*)d_in[3];
  const float* qkvb  = (const float*)d_in[4];
  const float* rpb   = (const float*)d_in[5];
  const float* projw = (const float*)d_in[6];
  const float* projb = (const float*)d_in[7];
  const float* ln2g  = (const float*)d_in[8];
  const float* ln2b  = (const float*)d_in[9];
  const float* fc1w  = (const float*)d_in[10];
  const float* fc1b  = (const float*)d_in[11];
  const float* fc2w  = (const float*)d_in[12];
  const float* fc2b  = (const float*)d_in[13];
  float* out = (float*)d_out;
  char* ws = (char*)d_ws;

  // ws layout (bytes): bf16 weights [0, 384K) | addtab @512K (2.4MB). Total < 3MB.
  unsigned short* wbuf = (unsigned short*)ws;
  unsigned short* wq = wbuf;                       // 384x128
  unsigned short* wp = wbuf + 49152;               // 128x128
  unsigned short* w1 = wbuf + 65536;               // 512x128
  unsigned short* w2 = wbuf + 131072;              // 128x512
  float* addtab = (float*)(ws + (512u << 10));

  k_cvt<<<768, 256, 0, stream>>>(qkvw, projw, fc1w, fc2w, wbuf);
  k_addtab<<<2401, 256, 0, stream>>>(rpb, addtab);
  k_attn<<<4096, 256, 0, stream>>>(x, ln1g, ln1b, wq, qkvb, wp, projb, addtab, out);
  k_mlp<<<3136, 256, 0, stream>>>(out, ln2g, ln2b, w1, fc1b, w2, fc2b);
}

// Round 4
// 561.608 us; speedup vs baseline: 2.0869x; 2.0869x over previous
//
#include <hip/hip_runtime.h>

#define SCALEF 0.17677669529663687f  // 32^-0.5

typedef __attribute__((ext_vector_type(8))) short short8;   // 8 bf16
typedef __attribute__((ext_vector_type(4))) float f32x4;
typedef __attribute__((ext_vector_type(4))) unsigned int u32x4;

__device__ __forceinline__ unsigned short f2bf(float f) {
  unsigned u = __builtin_bit_cast(unsigned, f);
  u = (u + 0x7FFFu + ((u >> 16) & 1u)) >> 16;
  return (unsigned short)u;
}
__device__ __forceinline__ short8 ld8(const unsigned short* p) { return *(const short8*)p; }
__device__ __forceinline__ unsigned cvtpk(float a, float b) {
  unsigned d;
  asm("v_cvt_pk_bf16_f32 %0, %1, %2" : "=v"(d) : "v"(a), "v"(b));
  return d;
}

// Build an MFMA A/B-frag (lane lo -> row, k = hi*8+e) from two 16x16 C-tiles
// whose ROWS are the k-dimension (tile tl=0 covers k 0..15, tl=1 covers 16..31).
// C layout: col=lane&15 (kept), row=4*hi+r (redistributed via shfl).
__device__ __forceinline__ short8 xform(f32x4 t0, f32x4 t1, int lo, int hi) {
  unsigned A01 = cvtpk(t0[0], t0[1]), A23 = cvtpk(t0[2], t0[3]);
  unsigned B01 = cvtpk(t1[0], t1[1]), B23 = cvtpk(t1[2], t1[3]);
  int s0 = ((2 * hi) & 3) * 16 + lo;
  int s1 = ((2 * hi + 1) & 3) * 16 + lo;
  bool up = hi >= 2;
  unsigned a, b;
  a = __shfl(A01, s0); b = __shfl(B01, s0); unsigned dw0 = up ? b : a;
  a = __shfl(A23, s0); b = __shfl(B23, s0); unsigned dw1 = up ? b : a;
  a = __shfl(A01, s1); b = __shfl(B01, s1); unsigned dw2 = up ? b : a;
  a = __shfl(A23, s1); b = __shfl(B23, s1); unsigned dw3 = up ? b : a;
  u32x4 v = {dw0, dw1, dw2, dw3};
  return __builtin_bit_cast(short8, v);
}

__device__ __forceinline__ float gelu_f(float x) {
  float z = 0.7978845608028654f * (x + 0.044715f * x * x * x);
  float e = __expf(2.0f * z);
  float th = 1.0f - 2.0f / (e + 1.0f);
  return 0.5f * x * (1.0f + th);
}

// ---------------------------------------------------------------- K0a: weights fp32 -> bf16
__global__ __launch_bounds__(256) void k_cvt(const float* qkvw, const float* projw,
                                             const float* fc1w, const float* fc2w,
                                             unsigned short* wbuf) {
  int i = blockIdx.x * 256 + threadIdx.x;
  float v;
  if (i < 49152) v = qkvw[i];
  else if (i < 65536) v = projw[i - 49152];
  else if (i < 131072) v = fc1w[i - 65536];
  else v = fc2w[i - 131072];
  wbuf[i] = f2bf(v);
}

// ---------------------------------------------------------------- K0b: bias+mask table, TRANSPOSED: at[w][h][j][i]
__device__ __forceinline__ int regio(int r) { return r < 49 ? 0 : (r < 53 ? 1 : 2); }

__global__ __launch_bounds__(256) void k_addtab(const float* rpb, float* at) {
  int idx = blockIdx.x * 256 + threadIdx.x;      // 64*4*49*49 = 614656 threads
  int i = idx % 49;                               // query token
  int tmp = idx / 49;
  int j = tmp % 49; tmp /= 49;                    // key token
  int h = tmp & 3;
  int w = tmp >> 2;
  int ih = i / 7, iw = i % 7, jh = j / 7, jw = j % 7;
  int rpi = (ih - jh + 6) * 13 + (iw - jw + 6);
  float bias = rpb[rpi * 4 + h];
  int wr = w >> 3, wc = w & 7;
  int idi = regio(wr * 7 + ih) * 3 + regio(wc * 7 + iw);
  int idj = regio(wr * 7 + jh) * 3 + regio(wc * 7 + jw);
  at[idx] = bias + ((idi != idj) ? -100.0f : 0.0f);
}

// ---------------------------------------------------------------- K1: fused LN1+QKV+attn+proj+residual
// 1 block/window, 1 wave/head. LDS 40.5KB -> 3 blocks/CU.
// Regions: X/attnout [0,12544) 49x256B swz ^((row&7)<<4)
//          K_h [12544+h*3136) 49x64B swz ^((tok&3)<<4)
//          V^T_h [25088+h*4096) 32x128B swz ^((d&7)<<4)
__global__ __launch_bounds__(256, 3) void k_attn(const float* __restrict__ x,
                                                 const float* __restrict__ g1,
                                                 const float* __restrict__ b1,
                                                 const unsigned short* __restrict__ wq,
                                                 const float* __restrict__ qb,
                                                 const unsigned short* __restrict__ wp,
                                                 const float* __restrict__ pb,
                                                 const float* __restrict__ addtab,
                                                 float* __restrict__ y) {
  __shared__ __align__(16) char L[41472];
  const int tid = threadIdx.x;
  const int wv = tid >> 6, l = tid & 63, lo = l & 15, hi = l >> 4;
  const int g = blockIdx.x;
  const int bimg = g >> 6, w_in = g & 63;
  const int wr = w_in >> 3, wc = w_in & 7;
  const int h = wv;
  char* Kh = L + 12544 + h * 3136;
  char* Vh = L + 25088 + h * 4096;
  const f32x4 fz = {0.f, 0.f, 0.f, 0.f};

  // ---- Phase 0: LN1 + roll(-3,-3) gather -> X (bf16, swizzled)
  for (int r = wv; r < 49; r += 4) {
    int ih = r / 7, iw = r - ih * 7;
    int oh = wr * 7 + ih + 3; if (oh >= 56) oh -= 56;
    int ow = wc * 7 + iw + 3; if (ow >= 56) ow -= 56;
    const float* src = x + ((size_t)bimg * 3136 + oh * 56 + ow) * 128;
    float2 v = *(const float2*)(src + l * 2);
    float s = v.x + v.y;
    #pragma unroll
    for (int off = 32; off; off >>= 1) s += __shfl_xor(s, off);
    float mu = s * (1.0f / 128.0f);
    float dx = v.x - mu, dy = v.y - mu;
    float q = dx * dx + dy * dy;
    #pragma unroll
    for (int off = 32; off; off >>= 1) q += __shfl_xor(q, off);
    float rs = rsqrtf(q * (1.0f / 128.0f) + 1e-5f);
    float o0 = dx * rs * g1[2 * l] + b1[2 * l];
    float o1 = dy * rs * g1[2 * l + 1] + b1[2 * l + 1];
    unsigned pk = (unsigned)f2bf(o0) | ((unsigned)f2bf(o1) << 16);
    *(unsigned*)(L + r * 256 + ((4 * l) ^ ((r & 7) << 4))) = pk;
  }
  __syncthreads();

  // ---- X fragments (lane lo -> token row, k = dim), shared by all 3 GEMMs
  short8 xb[4][4];
  #pragma unroll
  for (int t = 0; t < 4; t++) {
    int tok = t * 16 + lo; if (tok > 48) tok = 48;
    #pragma unroll
    for (int ks = 0; ks < 4; ks++)
      xb[t][ks] = *(const short8*)(L + tok * 256 + ((ks * 64 + hi * 16) ^ ((tok & 7) << 4)));
  }

  // ---- Q^T = Wq_h @ X^T  (C: row=qfeat, col=token) -> in-reg B-frags
  short8 qbf[4];
  {
    f32x4 cq[2][4] = {};
    #pragma unroll
    for (int ks = 0; ks < 4; ks++) {
      short8 wa0 = ld8(wq + (size_t)(h * 32 + lo) * 128 + ks * 32 + hi * 8);
      short8 wa1 = ld8(wq + (size_t)(h * 32 + 16 + lo) * 128 + ks * 32 + hi * 8);
      #pragma unroll
      for (int nt = 0; nt < 4; nt++) {
        cq[0][nt] = __builtin_amdgcn_mfma_f32_16x16x32_bf16(wa0, xb[nt][ks], cq[0][nt], 0, 0, 0);
        cq[1][nt] = __builtin_amdgcn_mfma_f32_16x16x32_bf16(wa1, xb[nt][ks], cq[1][nt], 0, 0, 0);
      }
    }
    float4 qb0 = *(const float4*)(qb + h * 32 + 4 * hi);
    float4 qb1 = *(const float4*)(qb + h * 32 + 16 + 4 * hi);
    #pragma unroll
    for (int nt = 0; nt < 4; nt++) {
      f32x4 t0 = cq[0][nt], t1 = cq[1][nt];
      t0[0] += qb0.x; t0[1] += qb0.y; t0[2] += qb0.z; t0[3] += qb0.w;
      t1[0] += qb1.x; t1[1] += qb1.y; t1[2] += qb1.z; t1[3] += qb1.w;
      qbf[nt] = xform(t0, t1, lo, hi);
    }
  }

  // ---- V^T = Wv_h @ X^T -> LDS [d][token]
  {
    f32x4 cv[2][4] = {};
    #pragma unroll
    for (int ks = 0; ks < 4; ks++) {
      short8 wa0 = ld8(wq + (size_t)(256 + h * 32 + lo) * 128 + ks * 32 + hi * 8);
      short8 wa1 = ld8(wq + (size_t)(256 + h * 32 + 16 + lo) * 128 + ks * 32 + hi * 8);
      #pragma unroll
      for (int nt = 0; nt < 4; nt++) {
        cv[0][nt] = __builtin_amdgcn_mfma_f32_16x16x32_bf16(wa0, xb[nt][ks], cv[0][nt], 0, 0, 0);
        cv[1][nt] = __builtin_amdgcn_mfma_f32_16x16x32_bf16(wa1, xb[nt][ks], cv[1][nt], 0, 0, 0);
      }
    }
    float4 vb0 = *(const float4*)(qb + 256 + h * 32 + 4 * hi);
    float4 vb1 = *(const float4*)(qb + 256 + h * 32 + 16 + 4 * hi);
    #pragma unroll
    for (int mt = 0; mt < 2; mt++) {
      #pragma unroll
      for (int nt = 0; nt < 4; nt++) {
        #pragma unroll
        for (int r = 0; r < 4; r++) {
          int d = mt * 16 + 4 * hi + r;
          int j = nt * 16 + lo;
          float bv = mt ? ((const float*)&vb1)[r] : ((const float*)&vb0)[r];
          *(unsigned short*)(Vh + d * 128 + ((2 * j) ^ ((d & 7) << 4))) = f2bf(cv[mt][nt][r] + bv);
        }
      }
    }
  }

  // ---- K = X @ Wk_h^T -> LDS [token][d]
  {
    f32x4 ck[4][2] = {};
    #pragma unroll
    for (int ks = 0; ks < 4; ks++) {
      short8 wb0 = ld8(wq + (size_t)(128 + h * 32 + lo) * 128 + ks * 32 + hi * 8);
      short8 wb1 = ld8(wq + (size_t)(128 + h * 32 + 16 + lo) * 128 + ks * 32 + hi * 8);
      #pragma unroll
      for (int mt = 0; mt < 4; mt++) {
        ck[mt][0] = __builtin_amdgcn_mfma_f32_16x16x32_bf16(xb[mt][ks], wb0, ck[mt][0], 0, 0, 0);
        ck[mt][1] = __builtin_amdgcn_mfma_f32_16x16x32_bf16(xb[mt][ks], wb1, ck[mt][1], 0, 0, 0);
      }
    }
    float kb0 = qb[128 + h * 32 + lo];
    float kb1 = qb[128 + h * 32 + 16 + lo];
    #pragma unroll
    for (int mt = 0; mt < 4; mt++) {
      #pragma unroll
      for (int nt = 0; nt < 2; nt++) {
        #pragma unroll
        for (int r = 0; r < 4; r++) {
          int tok = mt * 16 + 4 * hi + r;
          if (tok < 49) {
            int d = nt * 16 + lo;
            float bv = nt ? kb1 : kb0;
            *(unsigned short*)(Kh + tok * 64 + ((2 * d) ^ ((tok & 3) << 4))) = f2bf(ck[mt][nt][r] + bv);
          }
        }
      }
    }
  }
  __syncthreads();   // X dead block-wide; attnout may overwrite it later

  // ---- S^T = K @ Q^T  (C: row=j key token, col=i query token)
  f32x4 st[4][4];
  {
    short8 ka[4];
    #pragma unroll
    for (int jt = 0; jt < 4; jt++) {
      int tq = jt * 16 + lo; if (tq > 48) tq = 48;
      ka[jt] = *(const short8*)(Kh + tq * 64 + ((16 * hi) ^ ((tq & 3) << 4)));
    }
    #pragma unroll
    for (int jt = 0; jt < 4; jt++)
      #pragma unroll
      for (int it = 0; it < 4; it++)
        st[jt][it] = __builtin_amdgcn_mfma_f32_16x16x32_bf16(ka[jt], qbf[it], fz, 0, 0, 0);
  }

  // ---- softmax over j (rows): in-lane 16 values + shfl_xor(16,32)
  const float* at = addtab + ((size_t)w_in * 4 + h) * 2401;
  #pragma unroll
  for (int it = 0; it < 4; it++) {
    int i = it * 16 + lo;
    int ic = i > 48 ? 48 : i;
    float vv[4][4];
    #pragma unroll
    for (int jt = 0; jt < 4; jt++) {
      #pragma unroll
      for (int r = 0; r < 4; r++) {
        int jj = jt * 16 + 4 * hi + r;
        int jc = jj > 48 ? 48 : jj;
        float sv = st[jt][it][r] * SCALEF + at[jc * 49 + ic];
        vv[jt][r] = (jj < 49) ? sv : -1e30f;
      }
    }
    float m01, m23, mx = -1e30f;
    #pragma unroll
    for (int jt = 0; jt < 4; jt++) {
      m01 = fmaxf(vv[jt][0], vv[jt][1]);
      m23 = fmaxf(vv[jt][2], vv[jt][3]);
      mx = fmaxf(mx, fmaxf(m01, m23));
    }
    mx = fmaxf(mx, __shfl_xor(mx, 16));
    mx = fmaxf(mx, __shfl_xor(mx, 32));
    float sum = 0.0f;
    #pragma unroll
    for (int jt = 0; jt < 4; jt++)
      #pragma unroll
      for (int r = 0; r < 4; r++) {
        vv[jt][r] = __expf(vv[jt][r] - mx);
        sum += vv[jt][r];
      }
    sum += __shfl_xor(sum, 16);
    sum += __shfl_xor(sum, 32);
    float rinv = 1.0f / sum;
    #pragma unroll
    for (int jt = 0; jt < 4; jt++)
      #pragma unroll
      for (int r = 0; r < 4; r++)
        st[jt][it][r] = vv[jt][r] * rinv;
  }

  // ---- PV: out[i][d] = sum_j P[i][j] V[j][d]
  f32x4 o[4][2] = {};
  {
    short8 vf[2][2];
    #pragma unroll
    for (int td = 0; td < 2; td++) {
      int d = td * 16 + lo;
      #pragma unroll
      for (int ks = 0; ks < 2; ks++)
        vf[td][ks] = *(const short8*)(Vh + d * 128 + ((ks * 64 + 16 * hi) ^ ((d & 7) << 4)));
    }
    #pragma unroll
    for (int it = 0; it < 4; it++) {
      #pragma unroll
      for (int ks = 0; ks < 2; ks++) {
        short8 pf = xform(st[2 * ks][it], st[2 * ks + 1][it], lo, hi);
        #pragma unroll
        for (int td = 0; td < 2; td++)
          o[it][td] = __builtin_amdgcn_mfma_f32_16x16x32_bf16(pf, vf[td][ks], o[it][td], 0, 0, 0);
      }
    }
  }

  // ---- stage attnout into X region [token][c], swizzled
  #pragma unroll
  for (int it = 0; it < 4; it++)
    #pragma unroll
    for (int td = 0; td < 2; td++)
      #pragma unroll
      for (int r = 0; r < 4; r++) {
        int i = it * 16 + 4 * hi + r;
        if (i < 49) {
          int c = h * 32 + td * 16 + lo;
          *(unsigned short*)(L + i * 256 + ((2 * c) ^ ((i & 7) << 4))) = f2bf(o[it][td][r]);
        }
      }
  __syncthreads();

  // ---- proj + window-reverse + roll(+3) + residual; wave wv -> cols [wv*32, +32)
  f32x4 pacc[4][2] = {};
  #pragma unroll
  for (int ks = 0; ks < 4; ks++) {
    short8 wb0 = ld8(wp + (size_t)(wv * 32 + lo) * 128 + ks * 32 + hi * 8);
    short8 wb1 = ld8(wp + (size_t)(wv * 32 + 16 + lo) * 128 + ks * 32 + hi * 8);
    #pragma unroll
    for (int mt = 0; mt < 4; mt++) {
      int tok = mt * 16 + lo; if (tok > 48) tok = 48;
      short8 a = *(const short8*)(L + tok * 256 + ((ks * 64 + hi * 16) ^ ((tok & 7) << 4)));
      pacc[mt][0] = __builtin_amdgcn_mfma_f32_16x16x32_bf16(a, wb0, pacc[mt][0], 0, 0, 0);
      pacc[mt][1] = __builtin_amdgcn_mfma_f32_16x16x32_bf16(a, wb1, pacc[mt][1], 0, 0, 0);
    }
  }
  float pb0 = pb[wv * 32 + lo], pb1 = pb[wv * 32 + 16 + lo];
  #pragma unroll
  for (int mt = 0; mt < 4; mt++) {
    #pragma unroll
    for (int r = 0; r < 4; r++) {
      int tok = mt * 16 + 4 * hi + r;
      if (tok < 49) {
        int ih = tok / 7, iw = tok - ih * 7;
        int oh = wr * 7 + ih + 3; if (oh >= 56) oh -= 56;
        int ow = wc * 7 + iw + 3; if (ow >= 56) ow -= 56;
        size_t yrow = (size_t)bimg * 3136 + oh * 56 + ow;
        const float* xr = x + yrow * 128;
        float* yr = y + yrow * 128;
        int c0 = wv * 32 + lo, c1 = wv * 32 + 16 + lo;
        yr[c0] = pacc[mt][0][r] + pb0 + xr[c0];
        yr[c1] = pacc[mt][1][r] + pb1 + xr[c1];
      }
    }
  }
}

// ---------------------------------------------------------------- K2: fused LN2+fc1+GELU+fc2+residual (in-place)
// 512 threads (8 waves), 64 rows/block, 80KB LDS -> 2 blocks/CU = 16 waves/CU.
__global__ __launch_bounds__(512, 4) void k_mlp(float* __restrict__ y,
                                                const float* __restrict__ g2, const float* __restrict__ b2,
                                                const unsigned short* __restrict__ w1, const float* __restrict__ bias1,
                                                const unsigned short* __restrict__ w2, const float* __restrict__ bias2) {
  __shared__ __align__(16) char Xl[16384];   // 64 x 256B, swz ^((row&7)<<4)
  __shared__ __align__(16) char Hl[65536];   // 64 x 1024B, swz ^((row&7)<<4)
  int m0 = blockIdx.x * 64;
  int tid = threadIdx.x;
  int wv = tid >> 6, l = tid & 63, lo = l & 15, hi = l >> 4;

  // --- LN2: wave wv -> rows wv*8 .. +7
  #pragma unroll 1
  for (int i = 0; i < 8; i++) {
    int rloc = wv * 8 + i;
    int m = m0 + rloc;
    float2 v = *(const float2*)(y + (size_t)m * 128 + l * 2);
    float s = v.x + v.y;
    #pragma unroll
    for (int off = 32; off; off >>= 1) s += __shfl_xor(s, off);
    float mu = s * (1.0f / 128.0f);
    float dx = v.x - mu, dy = v.y - mu;
    float q = dx * dx + dy * dy;
    #pragma unroll
    for (int off = 32; off; off >>= 1) q += __shfl_xor(q, off);
    float rs = rsqrtf(q * (1.0f / 128.0f) + 1e-5f);
    float o0 = dx * rs * g2[2 * l] + b2[2 * l];
    float o1 = dy * rs * g2[2 * l + 1] + b2[2 * l + 1];
    unsigned pk = (unsigned)f2bf(o0) | ((unsigned)f2bf(o1) << 16);
    *(unsigned*)(Xl + rloc * 256 + ((4 * l) ^ ((rloc & 7) << 4))) = pk;
  }
  __syncthreads();

  // --- fc1 + GELU: wave wv -> cols [wv*64, +64), all 64 rows
  {
    f32x4 acc[4][4] = {};
    #pragma unroll
    for (int ks = 0; ks < 4; ks++) {
      short8 wb[4];
      #pragma unroll
      for (int nt = 0; nt < 4; nt++)
        wb[nt] = ld8(w1 + (size_t)(wv * 64 + nt * 16 + lo) * 128 + ks * 32 + hi * 8);
      #pragma unroll
      for (int mt = 0; mt < 4; mt++) {
        int row = mt * 16 + lo;
        short8 a = *(const short8*)(Xl + row * 256 + ((ks * 64 + hi * 16) ^ ((row & 7) << 4)));
        #pragma unroll
        for (int nt = 0; nt < 4; nt++)
          acc[mt][nt] = __builtin_amdgcn_mfma_f32_16x16x32_bf16(a, wb[nt], acc[mt][nt], 0, 0, 0);
      }
    }
    float b1v[4];
    #pragma unroll
    for (int nt = 0; nt < 4; nt++) b1v[nt] = bias1[wv * 64 + nt * 16 + lo];
    #pragma unroll
    for (int mt = 0; mt < 4; mt++) {
      #pragma unroll
      for (int nt = 0; nt < 4; nt++) {
        #pragma unroll
        for (int r = 0; r < 4; r++) {
          int row = mt * 16 + 4 * hi + r;
          int n = wv * 64 + nt * 16 + lo;
          float ge = gelu_f(acc[mt][nt][r] + b1v[nt]);
          *(unsigned short*)(Hl + row * 1024 + ((2 * n) ^ ((row & 7) << 4))) = f2bf(ge);
        }
      }
    }
  }
  __syncthreads();

  // --- fc2: wave wv -> cols [wv*16, +16), K=512
  {
    f32x4 acc2[4] = {};
    #pragma unroll 1
    for (int ks = 0; ks < 16; ks++) {
      short8 wb = ld8(w2 + (size_t)(wv * 16 + lo) * 512 + ks * 32 + hi * 8);
      #pragma unroll
      for (int mt = 0; mt < 4; mt++) {
        int row = mt * 16 + lo;
        short8 a = *(const short8*)(Hl + row * 1024 + ((ks * 64 + hi * 16) ^ ((row & 7) << 4)));
        acc2[mt] = __builtin_amdgcn_mfma_f32_16x16x32_bf16(a, wb, acc2[mt], 0, 0, 0);
      }
    }
    int c = wv * 16 + lo;
    float b2v = bias2[c];
    #pragma unroll
    for (int mt = 0; mt < 4; mt++) {
      #pragma unroll
      for (int r = 0; r < 4; r++) {
        int m = m0 + mt * 16 + 4 * hi + r;
        y[(size_t)m * 128 + c] = acc2[mt][r] + b2v + y[(size_t)m * 128 + c];
      }
    }
  }
}

// ---------------------------------------------------------------- launch
extern "C" void kernel_launch(void* const* d_in, const int* in_sizes, int n_in,
                              void* d_out, int out_size, void* d_ws, size_t ws_size,
                              hipStream_t stream) {
  const float* x     = (const float*)d_in[0];
  const float* ln1g  = (const float*)d_in[1];
  const float* ln1b  = (const float*)d_in[2];
  const float* qkvw  = (const float*)d_in[3];
  const float* qkvb  = (const float*)d_in[4];
  const float* rpb   = (const float*)d_in[5];
  const float* projw = (const float*)d_in[6];
  const float* projb = (const float*)d_in[7];
  const float* ln2g  = (const float*)d_in[8];
  const float* ln2b  = (const float*)d_in[9];
  const float* fc1w  = (const float*)d_in[10];
  const float* fc1b  = (const float*)d_in[11];
  const float* fc2w  = (const float*)d_in[12];
  const float* fc2b  = (const float*)d_in[13];
  float* out = (float*)d_out;
  char* ws = (char*)d_ws;

  // ws layout: bf16 weights [0, 384K) | addtab @512K (2.4MB). Total < 3MB.
  unsigned short* wbuf = (unsigned short*)ws;
  unsigned short* wq = wbuf;                       // 384x128
  unsigned short* wp = wbuf + 49152;               // 128x128
  unsigned short* w1 = wbuf + 65536;               // 512x128
  unsigned short* w2 = wbuf + 131072;              // 128x512
  float* addtab = (float*)(ws + (512u << 10));

  k_cvt<<<768, 256, 0, stream>>>(qkvw, projw, fc1w, fc2w, wbuf);
  k_addtab<<<2401, 256, 0, stream>>>(rpb, addtab);
  k_attn<<<4096, 256, 0, stream>>>(x, ln1g, ln1b, wq, qkvb, wp, projb, addtab, out);
  k_mlp<<<3136, 512, 0, stream>>>(out, ln2g, ln2b, w1, fc1b, w2, fc2b);
}